// Round 6
// baseline (812.194 us; speedup 1.0000x reference)
//
#include <hip/hip_runtime.h>
#include <hip/hip_bf16.h>

static constexpr int N = 512;    // state size == feature size
static constexpr int L = 16384;  // sequence length
static constexpr int SQX = 16;   // sq blocks occupy bx < SQX in MODE 0

typedef short s16x8 __attribute__((ext_vector_type(8)));
typedef float f32x4 __attribute__((ext_vector_type(4)));
using bf16 = __hip_bfloat16;

#define GPTR(p) ((const __attribute__((address_space(1))) void*)(p))
#define LPTR(p) ((__attribute__((address_space(3))) void*)(p))
__device__ __forceinline__ void gload16(const void* g, void* l) {
    __builtin_amdgcn_global_load_lds(GPTR(g), LPTR(l), 16, 0, 0);
}

// counted-wait + barrier; VN newest vmem ops may stay in flight (T3+T4)
#define FENCE_BARRIER(VN) do { \
    asm volatile("s_waitcnt vmcnt(" #VN ") lgkmcnt(0)" ::: "memory"); \
    __builtin_amdgcn_s_barrier(); \
    asm volatile("" ::: "memory"); } while (0)

__device__ __forceinline__ void split2(float v, ushort& h, ushort& l) {
    bf16 hb = __float2bfloat16(v);
    h = *reinterpret_cast<ushort*>(&hb);
    bf16 lb = __float2bfloat16(v - __bfloat162float(hb));
    l = *reinterpret_cast<ushort*>(&lb);
}

// ---------------- small setup kernels ----------------

__global__ void k_scale(const float* __restrict__ A, float* __restrict__ M, float h, int n) {
    int i = blockIdx.x * 256 + threadIdx.x;
    if (i < n) M[i] = A[i] * h;
}

// D0 = 2(M+M^2) (f32 + split), BL = I + M + M^2
__global__ void k_buildD(const float* __restrict__ M, const float* __restrict__ M2,
                         float* __restrict__ D0f, bf16* __restrict__ Dh,
                         bf16* __restrict__ Dl, float* __restrict__ BLm) {
    int i = blockIdx.x * 256 + threadIdx.x;
    if (i >= N * N) return;
    float m = M[i], m2 = M2[i];
    float d = 2.0f * (m + m2);
    D0f[i] = d;
    ushort h, l;
    split2(d, h, l);
    *reinterpret_cast<ushort*>(Dh + i) = h;
    *reinterpret_cast<ushort*>(Dl + i) = l;
    BLm[i] = (((i >> 9) == (i & (N - 1))) ? 1.0f : 0.0f) + m + m2;
}

// vectorized f32 -> (hi, lo) bf16 split, 4 elems/thread
__global__ void k_split4(const float* __restrict__ in, bf16* __restrict__ hi,
                         bf16* __restrict__ lo, int n4) {
    int i = blockIdx.x * 256 + threadIdx.x;
    if (i >= n4) return;
    float4 v = reinterpret_cast<const float4*>(in)[i];
    ushort ht[4], lt[4];
    split2(v.x, ht[0], lt[0]);
    split2(v.y, ht[1], lt[1]);
    split2(v.z, ht[2], lt[2]);
    split2(v.w, ht[3], lt[3]);
    *reinterpret_cast<ushort4*>(hi + 4 * (size_t)i) = *reinterpret_cast<ushort4*>(ht);
    *reinterpret_cast<ushort4*>(lo + 4 * (size_t)i) = *reinterpret_cast<ushort4*>(lt);
}

// 512x512 f32 transpose
__global__ void k_transpose(const float* __restrict__ in, float* __restrict__ out) {
    __shared__ float t[32][33];
    int bx = blockIdx.x * 32, by = blockIdx.y * 32;
    int tx = threadIdx.x, ty = threadIdx.y;  // block 32x8
#pragma unroll
    for (int j = 0; j < 32; j += 8) t[ty + j][tx] = in[(by + ty + j) * N + bx + tx];
    __syncthreads();
#pragma unroll
    for (int j = 0; j < 32; j += 8) out[(bx + ty + j) * N + by + tx] = t[tx][ty + j];
}

// transpose + f32 master + bf16 split of the transpose
__global__ void k_tsplit(const float* __restrict__ in, float* __restrict__ of,
                         bf16* __restrict__ oh, bf16* __restrict__ ol) {
    __shared__ float t[32][33];
    int bx = blockIdx.x * 32, by = blockIdx.y * 32;
    int tx = threadIdx.x, ty = threadIdx.y;
#pragma unroll
    for (int j = 0; j < 32; j += 8) t[ty + j][tx] = in[(by + ty + j) * N + bx + tx];
    __syncthreads();
#pragma unroll
    for (int j = 0; j < 32; j += 8) {
        float v = t[tx][ty + j];
        size_t off = (size_t)(bx + ty + j) * N + by + tx;
        of[off] = v;
        ushort h, l;
        split2(v, h, l);
        *reinterpret_cast<ushort*>(oh + off) = h;
        *reinterpret_cast<ushort*>(ol + off) = l;
    }
}

// ---------------- f32 NT GEMM 64x64 + fused bf16-split epilogue (setup only) ----
__global__ __launch_bounds__(256) void k_qsq(
    const float* __restrict__ Asrc, const float* __restrict__ Bmat,
    float* __restrict__ OUT, bf16* __restrict__ Sh, bf16* __restrict__ Sl, float scale) {
    __shared__ float As[32][64];
    __shared__ float Bs[32][64];
    const int tid = threadIdx.x;
    const int brow = blockIdx.x * 64;
    const int bcol = blockIdx.y * 64;
    const int tx = tid & 15, ty = tid >> 4;
    float acc[4][4] = {};

    for (int k0 = 0; k0 < N; k0 += 32) {
#pragma unroll
        for (int q = 0; q < 2; ++q) {
            int idx = tid * 2 + q;
            int row = idx >> 3;
            int kq = (idx & 7) << 2;
            float4 va = *(const float4*)(Asrc + (long)(brow + row) * N + k0 + kq);
            As[kq + 0][row] = va.x; As[kq + 1][row] = va.y;
            As[kq + 2][row] = va.z; As[kq + 3][row] = va.w;
            float4 vb = *(const float4*)(Bmat + (long)(bcol + row) * N + k0 + kq);
            Bs[kq + 0][row] = vb.x; Bs[kq + 1][row] = vb.y;
            Bs[kq + 2][row] = vb.z; Bs[kq + 3][row] = vb.w;
        }
        __syncthreads();
#pragma unroll
        for (int kk = 0; kk < 32; ++kk) {
            float a[4], b[4];
            *(float4*)&a[0] = *(const float4*)&As[kk][ty * 4];
            *(float4*)&b[0] = *(const float4*)&Bs[kk][tx * 4];
#pragma unroll
            for (int i = 0; i < 4; ++i)
#pragma unroll
                for (int j = 0; j < 4; ++j) acc[i][j] = fmaf(a[i], b[j], acc[i][j]);
        }
        __syncthreads();
    }
#pragma unroll
    for (int i = 0; i < 4; ++i) {
        long off = (long)(brow + ty * 4 + i) * N + bcol + tx * 4;
        float4 o = make_float4(acc[i][0] * scale, acc[i][1] * scale,
                               acc[i][2] * scale, acc[i][3] * scale);
        *(float4*)(OUT + off) = o;
        ushort ht[4], lt[4];
        split2(o.x, ht[0], lt[0]); split2(o.y, ht[1], lt[1]);
        split2(o.z, ht[2], lt[2]); split2(o.w, ht[3], lt[3]);
        *reinterpret_cast<ushort4*>(Sh + off) = *reinterpret_cast<ushort4*>(ht);
        *reinterpret_cast<ushort4*>(Sl + off) = *reinterpret_cast<ushort4*>(lt);
    }
}

// ---------------- main MFMA kernel: doubling round / plain GEMM ----------------
// MODE 0 (round): sq blocks (bx < SQX): Dnext = D^2 + 2D (both orientations);
//                 big blocks: Xo[i] = Xi[i] + Xi[i-s] + (Xi[i-s] @ D^T)  (f32 X)
//                 big rows rotated by shift/128 so GEMM blocks dispatch first.
// MODE 1 (plain): Xo = Xi @ Bp^T  (f32 out; Bu and final C GEMM)
// NM=1: 1 MFMA (Ahi@Bhi), LDS 3-deep;  NM=3: bf16x3, LDS 2-deep.
// Counted-vmcnt pipeline: loads stay in flight across raw s_barrier (T3+T4).
template <int NM, int MODE>
__global__ __launch_bounds__(256, (NM == 1 ? 3 : 2)) void k_round(
    const float* __restrict__ Xi, float* __restrict__ Xo,
    const bf16* __restrict__ Bph, const bf16* __restrict__ Bpl,
    const bf16* __restrict__ DTh, const bf16* __restrict__ DTl,
    const float* __restrict__ DTf,
    bf16* __restrict__ Dnh, bf16* __restrict__ Dnl,
    bf16* __restrict__ DTnh, bf16* __restrict__ DTnl, float* __restrict__ DTfn,
    int shift, int doSq)
{
    constexpr int SMEM = (NM == 1 ? 3 * 16384 : 2 * 32768);
    constexpr int BSTRIDE = (NM == 1 ? 16384 : 32768);  // per LDS buffer
    constexpr int BOFF = (NM == 1 ? 8192 : 16384);      // B region offset in buffer
    __shared__ char smem[SMEM];
    const int tid = threadIdx.x;
    const int wave = tid >> 6, lane = tid & 63;
    const int wm = wave >> 1, wn = wave & 1;
    const int rl = lane & 15, rh = lane >> 4;

    if (MODE == 0 && blockIdx.x < SQX) {
        // ======== D-squaring path (64 blocks, dispatch first) ========
        if (!doSq) return;
        int sidx = (int)blockIdx.x * (int)gridDim.y + (int)blockIdx.y;  // 0..63
        const int ti = (sidx >> 3) * 64, tj = (sidx & 7) * 64;

        f32x4 acc[2][2];
#pragma unroll
        for (int m = 0; m < 2; ++m)
#pragma unroll
            for (int n = 0; n < 2; ++n) acc[m][n] = (f32x4){0.f, 0.f, 0.f, 0.f};

        int row = tid >> 2, slot = tid & 3;
        int sp = slot ^ ((row >> 1) & 3);
        const char* pAh = (const char*)(DTh + (size_t)(ti + row) * N + sp * 8);
        const char* pAl = (const char*)(DTl + (size_t)(ti + row) * N + sp * 8);
        const char* pBh = (const char*)(Bph + (size_t)(tj + row) * N + sp * 8);
        const char* pBl = (const char*)(Bpl + (size_t)(tj + row) * N + sp * 8);
        const int wb = wave * 1024;

        gload16(pAh, smem + 0     + wb);
        gload16(pAl, smem + 4096  + wb);
        gload16(pBh, smem + 8192  + wb);
        gload16(pBl, smem + 12288 + wb);
        __syncthreads();

#pragma unroll
        for (int t = 0; t < 16; ++t) {
            const char* base = smem + (t & 1) * 16384;
            s16x8 ah[2], al[2], bh[2], bl[2];
#pragma unroll
            for (int m = 0; m < 2; ++m) {
                int r2 = wm * 32 + m * 16 + rl;
                int off = r2 * 64 + (rh ^ ((r2 >> 1) & 3)) * 16;
                ah[m] = *reinterpret_cast<const s16x8*>(base + off);
                al[m] = *reinterpret_cast<const s16x8*>(base + 4096 + off);
            }
#pragma unroll
            for (int n = 0; n < 2; ++n) {
                int r2 = wn * 32 + n * 16 + rl;
                int off = r2 * 64 + (rh ^ ((r2 >> 1) & 3)) * 16;
                bh[n] = *reinterpret_cast<const s16x8*>(base + 8192 + off);
                bl[n] = *reinterpret_cast<const s16x8*>(base + 12288 + off);
            }
            if (t + 1 < 16) {
                const int kb = (t + 1) * 64;
                char* nb = smem + ((t + 1) & 1) * 16384;
                gload16(pAh + kb, nb + 0     + wb);
                gload16(pAl + kb, nb + 4096  + wb);
                gload16(pBh + kb, nb + 8192  + wb);
                gload16(pBl + kb, nb + 12288 + wb);
            }
#pragma unroll
            for (int m = 0; m < 2; ++m)
#pragma unroll
                for (int n = 0; n < 2; ++n) {
                    acc[m][n] = __builtin_amdgcn_mfma_f32_16x16x32_bf16(ah[m], bh[n], acc[m][n], 0, 0, 0);
                    acc[m][n] = __builtin_amdgcn_mfma_f32_16x16x32_bf16(ah[m], bl[n], acc[m][n], 0, 0, 0);
                    acc[m][n] = __builtin_amdgcn_mfma_f32_16x16x32_bf16(al[m], bh[n], acc[m][n], 0, 0, 0);
                }
            __syncthreads();
        }

#pragma unroll
        for (int m = 0; m < 2; ++m)
#pragma unroll
            for (int n = 0; n < 2; ++n)
#pragma unroll
                for (int q = 0; q < 4; ++q) {
                    int i = ti + wm * 32 + m * 16 + rh * 4 + q;
                    int j = tj + wn * 32 + n * 16 + rl;
                    size_t off = (size_t)i * N + j;
                    float v = acc[m][n][q] + 2.0f * DTf[off];   // (D^2)^T + 2 D^T
                    DTfn[off] = v;
                    ushort h, l;
                    split2(v, h, l);
                    *reinterpret_cast<ushort*>(DTnh + off) = h;
                    *reinterpret_cast<ushort*>(DTnl + off) = l;
                    size_t offT = (size_t)j * N + i;
                    *reinterpret_cast<ushort*>(Dnh + offT) = h;
                    *reinterpret_cast<ushort*>(Dnl + offT) = l;
                }
        return;
    }

    // ======== big path: row-rotated so GEMM blocks dispatch first ========
    int bigbx = (MODE == 0) ? ((int)blockIdx.x - SQX) : (int)blockIdx.x;
    const int sb = (MODE == 0) ? (shift >> 7) : 0;
    int rowBlk = bigbx + sb;
    bool isCopy = false;
    if (MODE == 0 && rowBlk >= (L / 128)) { rowBlk -= (L / 128); isCopy = true; }
    const long brow = (long)rowBlk * 128;
    const int bcol = blockIdx.y * 128;

    if (MODE == 0 && isCopy) {
        // rows fully below shift: Xo = Xi, float4 copy
#pragma unroll
        for (int j = 0; j < 16; ++j) {
            int c = j * 256 + tid;
            long off = (brow + (c >> 5)) * N + bcol + (c & 31) * 4;
            *(float4*)(Xo + off) = *(const float4*)(Xi + off);
        }
        return;
    }

    f32x4 acc[4][4];
#pragma unroll
    for (int m = 0; m < 4; ++m)
#pragma unroll
        for (int n = 0; n < 4; ++n) acc[m][n] = (f32x4){0.f, 0.f, 0.f, 0.f};

    // A staging (reg): chunk q: row=idx>>2, slot=idx&3; write swizzled
    int aoff[2]; const float* aptr[2]; bool avalid[2];
#pragma unroll
    for (int q = 0; q < 2; ++q) {
        int idx = q * 256 + tid;
        int row = idx >> 2, slot = idx & 3;
        aoff[q] = row * 64 + (slot ^ ((row >> 1) & 3)) * 16;
        long gr = brow + row - (MODE == 0 ? (long)shift : 0);
        avalid[q] = (gr >= 0);
        aptr[q] = Xi + gr * N + slot * 8;
    }
    // B staging (gload_lds): linear LDS dest, pre-swizzled global source
    const char* bptrh[2]; const char* bptrl[2];
#pragma unroll
    for (int q = 0; q < 2; ++q) {
        int idx = q * 256 + tid;
        int row = idx >> 2, slot = idx & 3;
        int sp = slot ^ ((row >> 1) & 3);
        bptrh[q] = (const char*)(Bph + (size_t)(bcol + row) * N + sp * 8);
        bptrl[q] = (NM == 3) ? (const char*)(Bpl + (size_t)(bcol + row) * N + sp * 8) : nullptr;
    }
    const int wqb = wave * 1024;

    f32x4 Ar[2][2][2];  // [set][chunk][2x float4] — static-indexed (full unroll)
    auto loadA = [&](int t, int s) {
#pragma unroll
        for (int q = 0; q < 2; ++q) {
            if (avalid[q]) {
                Ar[s][q][0] = *reinterpret_cast<const f32x4*>(aptr[q] + t * 32);
                Ar[s][q][1] = *reinterpret_cast<const f32x4*>(aptr[q] + t * 32 + 4);
            } else {
                Ar[s][q][0] = (f32x4){0.f, 0.f, 0.f, 0.f};
                Ar[s][q][1] = (f32x4){0.f, 0.f, 0.f, 0.f};
            }
        }
    };
    auto writeA = [&](int s, char* buf) {
#pragma unroll
        for (int q = 0; q < 2; ++q) {
            float v[8];
            *reinterpret_cast<f32x4*>(&v[0]) = Ar[s][q][0];
            *reinterpret_cast<f32x4*>(&v[4]) = Ar[s][q][1];
            s16x8 h, l;
#pragma unroll
            for (int i = 0; i < 8; ++i) {
                ushort hh, ll;
                split2(v[i], hh, ll);
                h[i] = (short)hh; l[i] = (short)ll;
            }
            *reinterpret_cast<s16x8*>(buf + aoff[q]) = h;
            if (NM == 3) *reinterpret_cast<s16x8*>(buf + 8192 + aoff[q]) = l;
        }
    };
    auto gloadB = [&](int t, char* buf) {
#pragma unroll
        for (int q = 0; q < 2; ++q) {
            gload16(bptrh[q] + t * 64, buf + BOFF + q * 4096 + wqb);
            if (NM == 3) gload16(bptrl[q] + t * 64, buf + BOFF + 8192 + q * 4096 + wqb);
        }
    };

    if constexpr (NM == 1) {
        // -------- 3-deep pipeline, vmcnt(6) counted waits --------
        gloadB(0, smem + 0 * BSTRIDE); loadA(0, 0);
        gloadB(1, smem + 1 * BSTRIDE); loadA(1, 1);
        writeA(0, smem + 0 * BSTRIDE);
        FENCE_BARRIER(6);

#pragma unroll
        for (int t = 0; t < 16; ++t) {
            char* bcur = smem + (t % 3) * BSTRIDE;
            if (t + 2 < 16) {
                gloadB(t + 2, smem + ((t + 2) % 3) * BSTRIDE);
                loadA(t + 2, t & 1);
            }
            s16x8 a[4], b[4];
#pragma unroll
            for (int m = 0; m < 4; ++m) {
                int row = wm * 64 + m * 16 + rl;
                a[m] = *reinterpret_cast<const s16x8*>(bcur + row * 64 + (rh ^ ((row >> 1) & 3)) * 16);
            }
#pragma unroll
            for (int n = 0; n < 4; ++n) {
                int row = wn * 64 + n * 16 + rl;
                b[n] = *reinterpret_cast<const s16x8*>(bcur + BOFF + row * 64 + (rh ^ ((row >> 1) & 3)) * 16);
            }
#pragma unroll
            for (int m = 0; m < 4; ++m)
#pragma unroll
                for (int n = 0; n < 4; ++n)
                    acc[m][n] = __builtin_amdgcn_mfma_f32_16x16x32_bf16(a[m], b[n], acc[m][n], 0, 0, 0);
            if (t + 1 < 16) writeA((t + 1) & 1, smem + ((t + 1) % 3) * BSTRIDE);
            if (t < 15) {
                if (t < 13) FENCE_BARRIER(6);
                else        FENCE_BARRIER(0);
            }
        }
    } else {
        // -------- 2-deep pipeline, load-at-top / wait-at-bottom --------
        gloadB(0, smem + 0 * BSTRIDE); loadA(0, 0);
        writeA(0, smem + 0 * BSTRIDE);
        FENCE_BARRIER(0);

#pragma unroll
        for (int t = 0; t < 16; ++t) {
            char* bcur = smem + (t & 1) * BSTRIDE;
            char* bnxt = smem + ((t + 1) & 1) * BSTRIDE;
            if (t + 1 < 16) {
                gloadB(t + 1, bnxt);
                loadA(t + 1, (t + 1) & 1);
            }
            s16x8 ah[4], al[4], bh[4], bl[4];
#pragma unroll
            for (int m = 0; m < 4; ++m) {
                int row = wm * 64 + m * 16 + rl;
                int off = row * 64 + (rh ^ ((row >> 1) & 3)) * 16;
                ah[m] = *reinterpret_cast<const s16x8*>(bcur + off);
                al[m] = *reinterpret_cast<const s16x8*>(bcur + 8192 + off);
            }
#pragma unroll
            for (int n = 0; n < 4; ++n) {
                int row = wn * 64 + n * 16 + rl;
                int off = row * 64 + (rh ^ ((row >> 1) & 3)) * 16;
                bh[n] = *reinterpret_cast<const s16x8*>(bcur + BOFF + off);
                bl[n] = *reinterpret_cast<const s16x8*>(bcur + BOFF + 8192 + off);
            }
#pragma unroll
            for (int m = 0; m < 4; ++m)
#pragma unroll
                for (int n = 0; n < 4; ++n) {
                    acc[m][n] = __builtin_amdgcn_mfma_f32_16x16x32_bf16(ah[m], bh[n], acc[m][n], 0, 0, 0);
                    acc[m][n] = __builtin_amdgcn_mfma_f32_16x16x32_bf16(ah[m], bl[n], acc[m][n], 0, 0, 0);
                    acc[m][n] = __builtin_amdgcn_mfma_f32_16x16x32_bf16(al[m], bh[n], acc[m][n], 0, 0, 0);
                }
            if (t + 1 < 16) writeA((t + 1) & 1, bnxt);
            if (t < 15) FENCE_BARRIER(0);
        }
    }

    // epilogue: C/D layout col=lane&15, row=(lane>>4)*4+reg
    const long orow0 = brow + wm * 64;
    const int ocol0 = bcol + wn * 64;
#pragma unroll
    for (int m = 0; m < 4; ++m) {
#pragma unroll
        for (int q = 0; q < 4; ++q) {
            long gi = orow0 + m * 16 + rh * 4 + q;
            float* orow = Xo + gi * N + ocol0 + rl;
            if (MODE == 0) {
                const float* xr = Xi + gi * N + ocol0 + rl;
                const float* xs = xr - (long)shift * N;
                bool hasS = (gi >= (long)shift);
#pragma unroll
                for (int n = 0; n < 4; ++n) {
                    float v = acc[m][n][q] + xr[n * 16];
                    if (hasS) v += xs[n * 16];
                    orow[n * 16] = v;
                }
            } else {
#pragma unroll
                for (int n = 0; n < 4; ++n) orow[n * 16] = acc[m][n][q];
            }
        }
    }
}

// ---------------- launcher ----------------

extern "C" void kernel_launch(void* const* d_in, const int* in_sizes, int n_in,
                              void* d_out, int out_size, void* d_ws, size_t ws_size,
                              hipStream_t stream) {
    (void)in_sizes; (void)n_in; (void)out_size; (void)ws_size;
    const float* A = (const float*)d_in[0];
    const float* B = (const float*)d_in[1];
    const float* C = (const float*)d_in[2];
    const float* u = (const float*)d_in[3];

    const size_t NN = (size_t)N * N;
    const size_t LN = (size_t)L * N;

    float* X1 = (float*)d_out;   // ping buffer #2 (32 MB, overwritten by final GEMM)

    char* w = (char*)d_ws;
    float* X0 = (float*)w;     w += LN * 4;
    bf16 *Dh_[2], *Dl_[2], *DTh_[2], *DTl_[2];
    float* DTf_[2];
    for (int s = 0; s < 2; ++s) {
        Dh_[s]  = (bf16*)w;    w += NN * 2;
        Dl_[s]  = (bf16*)w;    w += NN * 2;
        DTh_[s] = (bf16*)w;    w += NN * 2;
        DTl_[s] = (bf16*)w;    w += NN * 2;
        DTf_[s] = (float*)w;   w += NN * 4;
    }
    float* M   = (float*)w;    w += NN * 4;
    float* MT  = (float*)w;    w += NN * 4;
    float* M2  = (float*)w;    w += NN * 4;
    float* BLm = (float*)w;    w += NN * 4;
    float* BT  = (float*)w;    w += NN * 4;
    float* Bbf = (float*)w;    w += NN * 4;
    float* D0f = (float*)w;    w += NN * 4;
    bf16* Bbh  = (bf16*)w;     w += NN * 2;
    bf16* Bbl  = (bf16*)w;     w += NN * 2;
    bf16* Ch   = (bf16*)w;     w += NN * 2;
    bf16* Cl   = (bf16*)w;     w += NN * 2;

    const float step = 1.0f / (float)L;

    dim3 b256(256);
    dim3 gEl((int)((NN + 255) / 256));
    dim3 bT(32, 8), gT(N / 32, N / 32);
    dim3 g64(N / 64, N / 64);
    dim3 gBig(L / 128, N / 128);
    dim3 gRound(SQX + L / 128, N / 128);   // sq blocks first, then 128 big rows
    dim3 gS4n((int)(NN / 4 / 256));

    // ---- setup ----
    k_scale<<<gEl, b256, 0, stream>>>(A, M, step * 0.5f, (int)NN);
    k_transpose<<<gT, bT, 0, stream>>>(M, MT);
    k_qsq<<<g64, b256, 0, stream>>>(M, MT, M2, Bbh, Bbl, 1.0f);             // M2 = M@M (splits scratch)
    k_buildD<<<gEl, b256, 0, stream>>>(M, M2, D0f, Dh_[0], Dl_[0], BLm);    // D_0, BL
    k_tsplit<<<gT, bT, 0, stream>>>(D0f, DTf_[0], DTh_[0], DTl_[0]);        // D_0^T
    k_transpose<<<gT, bT, 0, stream>>>(B, BT);
    k_qsq<<<g64, b256, 0, stream>>>(BLm, BT, Bbf, Bbh, Bbl, step);          // Bb (+ split)
    k_split4<<<gS4n, b256, 0, stream>>>(C, Ch, Cl, (int)(NN / 4));

    // ---- Bu = u @ Bb^T -> X0 ----
    k_round<3, 1><<<gBig, b256, 0, stream>>>(
        u, X0, Bbh, Bbl, nullptr, nullptr, nullptr,
        nullptr, nullptr, nullptr, nullptr, nullptr, 0, 0);

    // ---- 14 doubling rounds (D_{r+1} squaring fused, sq blocks first) ----
    for (int r = 0; r < 14; ++r) {
        int s = r & 1, nx = s ^ 1;
        float* Xi = (r & 1) ? X1 : X0;
        float* Xo = (r & 1) ? X0 : X1;
        int doSq = (r < 13) ? 1 : 0;
        if (r < 10)
            k_round<1, 0><<<gRound, b256, 0, stream>>>(
                Xi, Xo, Dh_[s], Dl_[s], DTh_[s], DTl_[s], DTf_[s],
                Dh_[nx], Dl_[nx], DTh_[nx], DTl_[nx], DTf_[nx], 1 << r, doSq);
        else
            k_round<3, 0><<<gRound, b256, 0, stream>>>(
                Xi, Xo, Dh_[s], Dl_[s], DTh_[s], DTl_[s], DTf_[s],
                Dh_[nx], Dl_[nx], DTh_[nx], DTl_[nx], DTf_[nx], 1 << r, doSq);
    }

    // ---- final: OUT = X0 @ C^T (f32, overwrites d_out) ----
    k_round<3, 1><<<gBig, b256, 0, stream>>>(
        X0, (float*)d_out, Ch, Cl, nullptr, nullptr, nullptr,
        nullptr, nullptr, nullptr, nullptr, nullptr, 0, 0);
}